// Round 16
// baseline (207.762 us; speedup 1.0000x reference)
//
#include <hip/hip_runtime.h>
#include <hip/hip_bf16.h>

#define VOCAB 50000
#define HID   256
#define BATCH 512
#define GH    768   // 3*H

typedef __attribute__((ext_vector_type(8))) __bf16 bf16x8;
typedef __attribute__((ext_vector_type(4))) float f32x4;
typedef __attribute__((ext_vector_type(4))) unsigned int u32x4;

union BFrag {
    bf16x8 v;
    u32x4  q;
    __bf16 b[8];
};

__device__ __forceinline__ float fast_sigmoid(float x) {
    return 1.0f / (1.0f + __expf(-x));
}
__device__ __forceinline__ float fast_tanh(float x) {
    return 1.0f - 2.0f / (1.0f + __expf(2.0f * x));
}

__device__ __forceinline__ void cvt8(BFrag& t, f32x4 lo, f32x4 hi) {
    t.b[0] = (__bf16)lo.x; t.b[1] = (__bf16)lo.y;
    t.b[2] = (__bf16)lo.z; t.b[3] = (__bf16)lo.w;
    t.b[4] = (__bf16)hi.x; t.b[5] = (__bf16)hi.y;
    t.b[6] = (__bf16)hi.z; t.b[7] = (__bf16)hi.w;
}

// 16B global -> LDS DMA. LDS dest must be wave-uniform base + lane*16.
__device__ __forceinline__ void gload_lds16(const void* g, void* l) {
    __builtin_amdgcn_global_load_lds(
        (const __attribute__((address_space(1))) unsigned int*)g,
        (__attribute__((address_space(3))) unsigned int*)l, 16, 0, 0);
}

// K3: logit = tanh(h1 @ w_out^T + b_out). m97-style: BOTH operands through
// double-buffered LDS; only accumulators are long-lived registers (no
// resident-B assumption — the R6/R10/R12/R15 spill trap).
// Block = 512 thr = 8 waves; tile = 128 vocab cols x all 512 batch rows
// (w_out HBM-fetched exactly once). 32 global steps (4 m-chunks x K/32):
//   stage(t+1): W f32->bf16 reg-staged, h1 via global_load_lds DMA
//   compute(t): wave (wc,wr) = 64 cols x 32 rows: 6 ds_read_b128 -> 8 MFMA
//   (swapped operands: W as A -> D rows = vocab -> dwordx4 stores, R14-proven)
// LDS k-major [g 0..3][col/row 0..127][16B]: frag reads = 256B contiguous per
// 16-lane group = conflict-free; staging writes lane-linear = conflict-free.
// One barrier/step; epilogue steps use counted vmcnt(8) (stores stay in
// flight, T4); other steps vmcnt(0) covers the DMA only.
__global__ __launch_bounds__(512, 4) void gemm_big(
    const unsigned short* __restrict__ Abf, const float* __restrict__ Wm,
    float* __restrict__ C, const float* __restrict__ bias)
{
    __shared__ char ldsW[2][8192];            // [g][col][16B] bf16, k-major
    __shared__ char ldsH[2][8192];            // [g][row][16B] bf16, k-major

    const int tid  = threadIdx.x;
    const int wid  = tid >> 6;                // 0..7
    const int lane = tid & 63;
    const int r    = lane & 15;
    const int gl   = lane >> 4;               // 0..3
    const int wc   = wid & 1;                 // col-half (64 cols)
    const int wr   = wid >> 1;                // row-quarter (32 rows)
    const int cb   = blockIdx.x * 128;        // vocab base

    // staging slot: thread -> (k-group sg, col/row sc)
    const int sg = tid >> 7;                  // 0..3
    const int sc = tid & 127;                 // 0..127
    const int wrow = (cb + sc < VOCAB) ? (cb + sc) : (VOCAB - 1);
    const float* wsrc0 = Wm + (size_t)wrow * 256 + sg * 8;

    // per-thread bias (4 consecutive vocab per m-group)
    f32x4 b4[4];
    #pragma unroll
    for (int m = 0; m < 4; m++) {
        int c0 = cb + wc * 64 + m * 16 + gl * 4;
        if (c0 > VOCAB - 4) c0 = VOCAB - 4;
        b4[m] = *reinterpret_cast<const f32x4*>(bias + c0);
    }

    f32x4 acc[4][2];
    f32x4 wlo, whi;                           // in-flight W staging regs

    // ---- prologue: stage step 0 into buf 0 ----
    {
        const f32x4* p = reinterpret_cast<const f32x4*>(wsrc0);
        wlo = __builtin_nontemporal_load(p);
        whi = __builtin_nontemporal_load(p + 1);
        gload_lds16(Abf + (size_t)sc * 256 + sg * 8, &ldsH[0][tid * 16]);
        BFrag w; cvt8(w, wlo, whi);
        *reinterpret_cast<u32x4*>(&ldsW[0][tid * 16]) = w.q;
        asm volatile("s_waitcnt vmcnt(0) lgkmcnt(0)\n\ts_barrier" ::: "memory");
    }

    for (int t = 0; t < 32; ++t) {
        const int s   = t & 7;
        const int buf = t & 1;

        // issue next-step staging loads early (latency hides under compute)
        if (t + 1 < 32) {
            const int s1  = (t + 1) & 7;
            const int mc1 = (t + 1) >> 3;
            const f32x4* p = reinterpret_cast<const f32x4*>(wsrc0 + s1 * 32);
            wlo = __builtin_nontemporal_load(p);
            whi = __builtin_nontemporal_load(p + 1);
            gload_lds16(Abf + (size_t)(mc1 * 128 + sc) * 256 + s1 * 32 + sg * 8,
                        &ldsH[buf ^ 1][tid * 16]);
        }

        if (s == 0) {
            #pragma unroll
            for (int m = 0; m < 4; m++)
                #pragma unroll
                for (int n = 0; n < 2; n++)
                    acc[m][n] = (f32x4){0.f, 0.f, 0.f, 0.f};
        }

        // compute step t
        BFrag wf[4], hf[2];
        #pragma unroll
        for (int m = 0; m < 4; m++)
            wf[m].q = *reinterpret_cast<const u32x4*>(
                &ldsW[buf][gl * 2048 + (wc * 64 + m * 16 + r) * 16]);
        #pragma unroll
        for (int n = 0; n < 2; n++)
            hf[n].q = *reinterpret_cast<const u32x4*>(
                &ldsH[buf][gl * 2048 + (wr * 32 + n * 16 + r) * 16]);
        #pragma unroll
        for (int m = 0; m < 4; m++)
            #pragma unroll
            for (int n = 0; n < 2; n++)
                acc[m][n] = __builtin_amdgcn_mfma_f32_16x16x32_bf16(
                    wf[m].v, hf[n].v, acc[m][n], 0, 0, 0);

        // epilogue at end of each m-chunk: 8 x dwordx4 per thread
        const bool last = (s == 7);
        if (last) {
            const int mb = (t >> 3) * 128 + wr * 32;
            #pragma unroll
            for (int m = 0; m < 4; m++) {
                const int v0 = cb + wc * 64 + m * 16 + gl * 4;
                if (v0 + 4 <= VOCAB) {
                    #pragma unroll
                    for (int n = 0; n < 2; n++) {
                        const int brow = mb + n * 16 + r;
                        f32x4 v;
                        #pragma unroll
                        for (int j = 0; j < 4; j++)
                            v[j] = fast_tanh(acc[m][n][j] + b4[m][j]);
                        *reinterpret_cast<f32x4*>(&C[(size_t)brow * VOCAB + v0]) = v;
                    }
                }
            }
        }

        if (t + 1 < 32) {
            // late half of staging: convert + ds_write (W-loads long done)
            BFrag w; cvt8(w, wlo, whi);
            *reinterpret_cast<u32x4*>(&ldsW[buf ^ 1][tid * 16]) = w.q;
            if (last)   // 8 stores issued after the DMA -> vmcnt(8) = DMA done
                asm volatile("s_waitcnt vmcnt(8) lgkmcnt(0)\n\ts_barrier" ::: "memory");
            else
                asm volatile("s_waitcnt vmcnt(0) lgkmcnt(0)\n\ts_barrier" ::: "memory");
        }
    }
}

// K1: hproj = h0 @ w_hh^T  (512 x 768, K=256). R13/R14-proven small kernel.
__global__ __launch_bounds__(256, 4) void gemm_h(
    const float* __restrict__ A, const float* __restrict__ Bm,
    float* __restrict__ C)
{
    __shared__ char ldsA[16384];              // 32 rows x 256 bf16, swizzled

    const int tid  = threadIdx.x;
    const int wid  = tid >> 6;
    const int lane = tid & 63;
    const int r    = lane & 15;
    const int g    = lane >> 4;
    const int col  = blockIdx.x * 64 + wid * 16 + r;    // < 768 always
    const int mbase = blockIdx.y * 32;

    BFrag bf[8];
    {
        const f32x4* wrow = reinterpret_cast<const f32x4*>(Bm + (size_t)col * 256);
        #pragma unroll
        for (int kk = 0; kk < 8; kk++)
            cvt8(bf[kk], wrow[kk * 8 + g * 2], wrow[kk * 8 + g * 2 + 1]);
    }

    {
        const f32x4* src = reinterpret_cast<const f32x4*>(A + (size_t)mbase * 256);
        #pragma unroll
        for (int i = 0; i < 4; i++) {
            int u = tid + i * 256;
            int row = u >> 5, jj = u & 31;
            BFrag t; cvt8(t, src[2 * u], src[2 * u + 1]);
            int byte = row * 512 + ((jj ^ (row & 7)) << 4);
            *reinterpret_cast<u32x4*>(&ldsA[byte]) = t.q;
        }
    }
    __syncthreads();

    f32x4 acc0 = (f32x4){0.f, 0.f, 0.f, 0.f};
    f32x4 acc1 = (f32x4){0.f, 0.f, 0.f, 0.f};
    #pragma unroll
    for (int kk = 0; kk < 8; kk++) {
        const int s0 = r * 512 + ((((kk << 2) + g) ^ (r & 7)) << 4);
        BFrag a0, a1;
        a0.q = *reinterpret_cast<const u32x4*>(&ldsA[s0]);
        a1.q = *reinterpret_cast<const u32x4*>(&ldsA[s0 + 8192]);
        acc0 = __builtin_amdgcn_mfma_f32_16x16x32_bf16(a0.v, bf[kk].v, acc0, 0, 0, 0);
        acc1 = __builtin_amdgcn_mfma_f32_16x16x32_bf16(a1.v, bf[kk].v, acc1, 0, 0, 0);
    }

    const int rowb = mbase + g * 4;
    #pragma unroll
    for (int j = 0; j < 4; j++) {
        C[(size_t)(rowb + j) * GH + col]      = acc0[j];
        C[(size_t)(rowb + 16 + j) * GH + col] = acc1[j];
    }
}

// K2: GRU gates. One block per batch row, thread = k. Writes h1 (f32, d_out
// tail) and h1 bf16 row-major (K3's streamed operand).
__global__ __launch_bounds__(256) void gru_gate(
    const int* __restrict__ inp, const float* __restrict__ hidden,
    const float* __restrict__ w_ih, const float* __restrict__ b_ih,
    const float* __restrict__ b_hh, const float* __restrict__ hproj,
    float* __restrict__ h1out, unsigned short* __restrict__ h1bf)
{
    const int b = blockIdx.x;
    const int k = threadIdx.x;
    const int c = inp[b];

    float xr = w_ih[(size_t)k * VOCAB + c]         + b_ih[k];
    float xz = w_ih[(size_t)(k + 256) * VOCAB + c] + b_ih[k + 256];
    float xn = w_ih[(size_t)(k + 512) * VOCAB + c] + b_ih[k + 512];

    float hr = hproj[b * GH + k]       + b_hh[k];
    float hz = hproj[b * GH + 256 + k] + b_hh[k + 256];
    float hn = hproj[b * GH + 512 + k] + b_hh[k + 512];

    float rg = fast_sigmoid(xr + hr);
    float zg = fast_sigmoid(xz + hz);
    float ng = fast_tanh(xn + rg * hn);
    float h0 = hidden[b * HID + k];
    float h1 = (1.0f - zg) * ng + zg * h0;

    h1out[b * HID + k] = h1;
    __bf16 hb = (__bf16)h1;
    h1bf[b * HID + k] = __builtin_bit_cast(unsigned short, hb);
}

extern "C" void kernel_launch(void* const* d_in, const int* in_sizes, int n_in,
                              void* d_out, int out_size, void* d_ws, size_t ws_size,
                              hipStream_t stream) {
    const int*   input  = (const int*)  d_in[0];
    // d_in[1] = target (unused)
    const float* hidden = (const float*)d_in[2];
    const float* w_ih   = (const float*)d_in[3];
    const float* w_hh   = (const float*)d_in[4];
    const float* b_ih   = (const float*)d_in[5];
    const float* b_hh   = (const float*)d_in[6];
    const float* w_out  = (const float*)d_in[7];
    const float* b_out  = (const float*)d_in[8];

    float* logit = (float*)d_out;                            // [512, 50000]
    float* h1    = (float*)d_out + (size_t)BATCH * VOCAB;    // [512, 256]

    float*          hproj = (float*)d_ws;                                   // 1.5 MB
    unsigned short* h1bf  = (unsigned short*)((char*)d_ws + (size_t)BATCH * GH * 4);

    // K1: hproj = h0 @ w_hh^T — grid (12, 16)
    dim3 g1(GH / 64, BATCH / 32);
    gemm_h<<<g1, 256, 0, stream>>>(hidden, w_hh, hproj);

    // K2: gates -> h1 (f32) + h1bf (row-major bf16)
    gru_gate<<<BATCH, 256, 0, stream>>>(input, hidden, w_ih, b_ih, b_hh, hproj,
                                        h1, h1bf);

    // K3: logit = tanh(h1 @ w_out^T + b_out) — 391 blocks x 512 threads
    dim3 g3((VOCAB + 127) / 128, 1);
    gemm_big<<<g3, 512, 0, stream>>>(h1bf, w_out, logit, b_out);
}